// Round 12
// baseline (38.870 us; speedup 1.0000x reference)
//
#include <hip/hip_runtime.h>

#define BATCH 256
#define DIM   4096
#define NS    32                  // k-splits; chunk = 128 elems
#define CHUNK (DIM / NS)          // 128 B per row-chunk (u8)
#define GPC   8                   // uint4 groups per chunk
#define TJ    8                   // j rows per block
#define NJB   (BATCH / TJ)        // 32 j-blocks
#define NREP  3                   // diagnostic: repeat full SAD computation

typedef unsigned long long ull;
typedef unsigned u32x4 __attribute__((ext_vector_type(4)));

// acc += sum_4bytes |a.b - b.b| ; b from SGPR (VOP3: 1 SGPR src legal)
#define SADS(acc, a, b) asm("v_sad_u8 %0, %1, %2, %0" : "+v"(acc) : "v"(a), "s"(b))
// genuine scalar load: 16B of row-major b-data into an SGPR quad
#define SLOADX4(dst, base, off) \
    asm volatile("s_load_dwordx4 %0, %1, " off : "=s"(dst) : "s"(base))

__device__ __forceinline__ unsigned quant_word(float4 v) {
    int q0 = __float2int_rn(fminf(fmaxf(fmaf(v.x, 16.0f, 128.0f), 0.0f), 255.0f));
    int q1 = __float2int_rn(fminf(fmaxf(fmaf(v.y, 16.0f, 128.0f), 0.0f), 255.0f));
    int q2 = __float2int_rn(fminf(fmaxf(fmaf(v.z, 16.0f, 128.0f), 0.0f), 255.0f));
    int q3 = __float2int_rn(fminf(fmaxf(fmaf(v.w, 16.0f, 128.0f), 0.0f), 255.0f));
    return (unsigned)q0 | ((unsigned)q1 << 8) | ((unsigned)q2 << 16) | ((unsigned)q3 << 24);
}

// fp32 -> u8 (scale 16, offset 128). qT transposed group-packed (a-side
// coalesced uint4 loads); qR row-major (b-side contiguous s_load).
__global__ __launch_bounds__(256)
void quantize_t(const float* __restrict__ x, const float* __restrict__ y,
                unsigned* __restrict__ qTx, unsigned* __restrict__ qTy,
                unsigned* __restrict__ qRx, unsigned* __restrict__ qRy) {
    const int b = blockIdx.x;             // 0..511
    const int i = b & 255;
    const float* src = (b < 256) ? x : y;
    unsigned* qT = (b < 256) ? qTx : qTy;
    unsigned* qR = (b < 256) ? qRx : qRy;
    const int t = threadIdx.x;
#pragma unroll
    for (int g = 0; g < 4; ++g) {
        const int w = g * 256 + t;
        float4 v = *(const float4*)(src + (size_t)i * DIM + (size_t)w * 4);
        const unsigned word = quant_word(v);
        qT[(size_t)(w >> 2) * 1024 + (size_t)i * 4 + (w & 3)] = word;
        qR[(size_t)i * 1024 + w] = word;
    }
}

// r5 core + 4-way accumulator chains, repeated NREP times (idempotent stores)
// so this dispatch's duration exceeds the harness fills and surfaces in the
// top-5 profile WITH its counters. T_sad = (dur - overhead)/NREP.
__global__ __launch_bounds__(256, 4)
void pairwise_sad(const u32x4* __restrict__ xg, const u32x4* __restrict__ yg,
                  const unsigned char* __restrict__ xr, const unsigned char* __restrict__ yr,
                  unsigned* __restrict__ Pp, unsigned* __restrict__ Qp) {
    const int jb = blockIdx.x;            // 0..NJB-1
    const int s  = blockIdx.y;            // 0..NS-1
    const int i  = threadIdx.x;           // my row
    const int g0 = s * GPC;

#pragma unroll 1
    for (int rep = 0; rep < NREP; ++rep) {
        u32x4 ax[GPC], ay[GPC];
#pragma unroll
        for (int g = 0; g < GPC; ++g) {
            ax[g] = xg[(size_t)(g0 + g) * 256 + i];   // coalesced 1KB/instr
            ay[g] = yg[(size_t)(g0 + g) * 256 + i];
        }

        const int j0 = jb * TJ;
        unsigned accx[TJ], accy[TJ];
#pragma unroll
        for (int jj = 0; jj < TJ; ++jj) {
            const unsigned char* bxp = xr + (size_t)(j0 + jj) * DIM + s * CHUNK;
            const unsigned char* byp = yr + (size_t)(j0 + jj) * DIM + s * CHUNK;
            u32x4 bx[GPC], by[GPC];
            SLOADX4(bx[0], bxp, "0x0");  SLOADX4(bx[1], bxp, "0x10");
            SLOADX4(bx[2], bxp, "0x20"); SLOADX4(bx[3], bxp, "0x30");
            SLOADX4(bx[4], bxp, "0x40"); SLOADX4(bx[5], bxp, "0x50");
            SLOADX4(bx[6], bxp, "0x60"); SLOADX4(bx[7], bxp, "0x70");
            SLOADX4(by[0], byp, "0x0");  SLOADX4(by[1], byp, "0x10");
            SLOADX4(by[2], byp, "0x20"); SLOADX4(by[3], byp, "0x30");
            SLOADX4(by[4], byp, "0x40"); SLOADX4(by[5], byp, "0x50");
            SLOADX4(by[6], byp, "0x60"); SLOADX4(by[7], byp, "0x70");
            asm volatile("s_waitcnt lgkmcnt(0)");
            __builtin_amdgcn_sched_barrier(0);   // rule #18

            // 8 independent chains of 4 SADs (was 4 chains of 8)
            unsigned px0 = 0, px1 = 0, px2 = 0, px3 = 0;
            unsigned py0 = 0, py1 = 0, py2 = 0, py3 = 0;
            SADS(px0, ax[0].x, bx[0].x); SADS(px1, ax[0].y, bx[0].y);
            SADS(px2, ax[0].z, bx[0].z); SADS(px3, ax[0].w, bx[0].w);
            SADS(py0, ay[0].x, by[0].x); SADS(py1, ay[0].y, by[0].y);
            SADS(py2, ay[0].z, by[0].z); SADS(py3, ay[0].w, by[0].w);
            SADS(px0, ax[1].x, bx[1].x); SADS(px1, ax[1].y, bx[1].y);
            SADS(px2, ax[1].z, bx[1].z); SADS(px3, ax[1].w, bx[1].w);
            SADS(py0, ay[1].x, by[1].x); SADS(py1, ay[1].y, by[1].y);
            SADS(py2, ay[1].z, by[1].z); SADS(py3, ay[1].w, by[1].w);
            SADS(px0, ax[2].x, bx[2].x); SADS(px1, ax[2].y, bx[2].y);
            SADS(px2, ax[2].z, bx[2].z); SADS(px3, ax[2].w, bx[2].w);
            SADS(py0, ay[2].x, by[2].x); SADS(py1, ay[2].y, by[2].y);
            SADS(py2, ay[2].z, by[2].z); SADS(py3, ay[2].w, by[2].w);
            SADS(px0, ax[3].x, bx[3].x); SADS(px1, ax[3].y, bx[3].y);
            SADS(px2, ax[3].z, bx[3].z); SADS(px3, ax[3].w, bx[3].w);
            SADS(py0, ay[3].x, by[3].x); SADS(py1, ay[3].y, by[3].y);
            SADS(py2, ay[3].z, by[3].z); SADS(py3, ay[3].w, by[3].w);
            SADS(px0, ax[4].x, bx[4].x); SADS(px1, ax[4].y, bx[4].y);
            SADS(px2, ax[4].z, bx[4].z); SADS(px3, ax[4].w, bx[4].w);
            SADS(py0, ay[4].x, by[4].x); SADS(py1, ay[4].y, by[4].y);
            SADS(py2, ay[4].z, by[4].z); SADS(py3, ay[4].w, by[4].w);
            SADS(px0, ax[5].x, bx[5].x); SADS(px1, ax[5].y, bx[5].y);
            SADS(px2, ax[5].z, bx[5].z); SADS(px3, ax[5].w, bx[5].w);
            SADS(py0, ay[5].x, by[5].x); SADS(py1, ay[5].y, by[5].y);
            SADS(py2, ay[5].z, by[5].z); SADS(py3, ay[5].w, by[5].w);
            SADS(px0, ax[6].x, bx[6].x); SADS(px1, ax[6].y, bx[6].y);
            SADS(px2, ax[6].z, bx[6].z); SADS(px3, ax[6].w, bx[6].w);
            SADS(py0, ay[6].x, by[6].x); SADS(py1, ay[6].y, by[6].y);
            SADS(py2, ay[6].z, by[6].z); SADS(py3, ay[6].w, by[6].w);
            SADS(px0, ax[7].x, bx[7].x); SADS(px1, ax[7].y, bx[7].y);
            SADS(px2, ax[7].z, bx[7].z); SADS(px3, ax[7].w, bx[7].w);
            SADS(py0, ay[7].x, by[7].x); SADS(py1, ay[7].y, by[7].y);
            SADS(py2, ay[7].z, by[7].z); SADS(py3, ay[7].w, by[7].w);
            accx[jj] = (px0 + px1) + (px2 + px3);
            accy[jj] = (py0 + py1) + (py2 + py3);
        }

        // u16 partials (<= 128*255 = 32640), layout Pp[s][i][j]; idempotent
        const size_t off16 = ((size_t)s * BATCH + i) * BATCH + j0;
        uint4 pv = make_uint4(accx[0] | (accx[1] << 16), accx[2] | (accx[3] << 16),
                              accx[4] | (accx[5] << 16), accx[6] | (accx[7] << 16));
        uint4 qv = make_uint4(accy[0] | (accy[1] << 16), accy[2] | (accy[3] << 16),
                              accy[4] | (accy[5] << 16), accy[6] | (accy[7] << 16));
        *(uint4*)(Pp + off16 / 2) = pv;
        *(uint4*)(Qp + off16 / 2) = qv;
    }
}

// out[i] = -sum_j (sum_s P)(sum_s Q) / (16*4096)^2 — fixed-order, deterministic.
__global__ __launch_bounds__(256)
void reduce_out(const unsigned short* __restrict__ Pp, const unsigned short* __restrict__ Qp,
                float* __restrict__ out) {
    const int i = blockIdx.x;
    const int t = threadIdx.x;
    const int w = t >> 6, l = t & 63;

    unsigned p[4] = {0, 0, 0, 0}, q[4] = {0, 0, 0, 0};
#pragma unroll
    for (int ss = 0; ss < NS / 4; ++ss) {
        const int s = w * (NS / 4) + ss;
        const size_t base = ((size_t)s * BATCH + i) * BATCH + 4 * l;
        uint2 pv = *(const uint2*)(Pp + base);
        uint2 qv = *(const uint2*)(Qp + base);
        p[0] += pv.x & 0xffffu; p[1] += pv.x >> 16;
        p[2] += pv.y & 0xffffu; p[3] += pv.y >> 16;
        q[0] += qv.x & 0xffffu; q[1] += qv.x >> 16;
        q[2] += qv.y & 0xffffu; q[3] += qv.y >> 16;
    }

    __shared__ unsigned rp[4][64][4], rq[4][64][4];
#pragma unroll
    for (int e = 0; e < 4; ++e) { rp[w][l][e] = p[e]; rq[w][l][e] = q[e]; }
    __syncthreads();

    if (t < 64) {
        const float c2 = 1.0f / (16.0f * 4096.0f);
        float v = 0.0f;
#pragma unroll
        for (int e = 0; e < 4; ++e) {
            unsigned P = rp[0][t][e] + rp[1][t][e] + rp[2][t][e] + rp[3][t][e];
            unsigned Q = rq[0][t][e] + rq[1][t][e] + rq[2][t][e] + rq[3][t][e];
            v += ((float)P * c2) * ((float)Q * c2);
        }
#pragma unroll
        for (int off = 32; off >= 1; off >>= 1)
            v += __shfl_down(v, off, 64);
        if (t == 0) out[i] = -v;
    }
}

extern "C" void kernel_launch(void* const* d_in, const int* in_sizes, int n_in,
                              void* d_out, int out_size, void* d_ws, size_t ws_size,
                              hipStream_t stream) {
    const float* x = (const float*)d_in[0];
    const float* y = (const float*)d_in[1];
    float* out = (float*)d_out;

    // ws: qTx 1MB | qTy 1MB | qRx 1MB | qRy 1MB | Pp u16 4MB | Qp u16 4MB
    unsigned* qTx = (unsigned*)d_ws;
    unsigned* qTy = qTx + (size_t)BATCH * (DIM / 4);
    unsigned* qRx = qTy + (size_t)BATCH * (DIM / 4);
    unsigned* qRy = qRx + (size_t)BATCH * (DIM / 4);
    unsigned short* Pp = (unsigned short*)(qRy + (size_t)BATCH * (DIM / 4));
    unsigned short* Qp = Pp + (size_t)NS * BATCH * BATCH;

    quantize_t<<<512, 256, 0, stream>>>(x, y, qTx, qTy, qRx, qRy);
    pairwise_sad<<<dim3(NJB, NS), 256, 0, stream>>>(
        (const u32x4*)qTx, (const u32x4*)qTy,
        (const unsigned char*)qRx, (const unsigned char*)qRy,
        (unsigned*)Pp, (unsigned*)Qp);
    reduce_out<<<BATCH, 256, 0, stream>>>(Pp, Qp, out);
}

// Round 13
// 30.165 us; speedup vs baseline: 1.2886x; 1.2886x over previous
//
#include <hip/hip_runtime.h>

#define BATCH 256
#define DIM   4096
#define NS    32                  // k-splits; chunk = 128 elems
#define CHUNK (DIM / NS)          // 128 B per row-chunk (u8)
#define GPC   8                   // uint4 groups per chunk
#define TJ    8                   // j rows per block
#define NJB   (BATCH / TJ)        // 32 j-blocks
#define QREP  5                   // diagnostic: amplify quantize only

typedef unsigned long long ull;
typedef unsigned u32x4 __attribute__((ext_vector_type(4)));

// acc += sum_4bytes |a.b - b.b| ; b from SGPR (VOP3: 1 SGPR src legal)
#define SADS(acc, a, b) asm("v_sad_u8 %0, %1, %2, %0" : "+v"(acc) : "v"(a), "s"(b))
// genuine scalar load: 16B of row-major b-data into an SGPR quad
#define SLOADX4(dst, base, off) \
    asm volatile("s_load_dwordx4 %0, %1, " off : "=s"(dst) : "s"(base))

__device__ __forceinline__ unsigned quant_word(float4 v) {
    int q0 = __float2int_rn(fminf(fmaxf(fmaf(v.x, 16.0f, 128.0f), 0.0f), 255.0f));
    int q1 = __float2int_rn(fminf(fmaxf(fmaf(v.y, 16.0f, 128.0f), 0.0f), 255.0f));
    int q2 = __float2int_rn(fminf(fmaxf(fmaf(v.z, 16.0f, 128.0f), 0.0f), 255.0f));
    int q3 = __float2int_rn(fminf(fmaxf(fmaf(v.w, 16.0f, 128.0f), 0.0f), 255.0f));
    return (unsigned)q0 | ((unsigned)q1 << 8) | ((unsigned)q2 << 16) | ((unsigned)q3 << 24);
}

// fp32 -> u8 (scale 16, offset 128). Repeated QREP times (idempotent; memory
// clobber prevents cross-rep merging) so its cost surfaces: dur ~ oh + 5q + s + r.
__global__ __launch_bounds__(256)
void quantize_t(const float* __restrict__ x, const float* __restrict__ y,
                unsigned* __restrict__ qTx, unsigned* __restrict__ qTy,
                unsigned* __restrict__ qRx, unsigned* __restrict__ qRy) {
    const int b = blockIdx.x;             // 0..511
    const int i = b & 255;
    const float* src = (b < 256) ? x : y;
    unsigned* qT = (b < 256) ? qTx : qTy;
    unsigned* qR = (b < 256) ? qRx : qRy;
    const int t = threadIdx.x;
#pragma unroll 1
    for (int rep = 0; rep < QREP; ++rep) {
#pragma unroll
        for (int g = 0; g < 4; ++g) {
            const int w = g * 256 + t;
            float4 v = *(const float4*)(src + (size_t)i * DIM + (size_t)w * 4);
            const unsigned word = quant_word(v);
            qT[(size_t)(w >> 2) * 1024 + (size_t)i * 4 + (w & 3)] = word;
            qR[(size_t)i * 1024 + w] = word;
        }
        asm volatile("" ::: "memory");    // force real re-execution per rep
    }
}

// r12 core (4-way accumulator chains), single pass.
__global__ __launch_bounds__(256, 4)
void pairwise_sad(const u32x4* __restrict__ xg, const u32x4* __restrict__ yg,
                  const unsigned char* __restrict__ xr, const unsigned char* __restrict__ yr,
                  unsigned* __restrict__ Pp, unsigned* __restrict__ Qp) {
    const int jb = blockIdx.x;            // 0..NJB-1
    const int s  = blockIdx.y;            // 0..NS-1
    const int i  = threadIdx.x;           // my row
    const int g0 = s * GPC;

    u32x4 ax[GPC], ay[GPC];
#pragma unroll
    for (int g = 0; g < GPC; ++g) {
        ax[g] = xg[(size_t)(g0 + g) * 256 + i];   // coalesced 1KB/instr
        ay[g] = yg[(size_t)(g0 + g) * 256 + i];
    }

    const int j0 = jb * TJ;
    unsigned accx[TJ], accy[TJ];
#pragma unroll
    for (int jj = 0; jj < TJ; ++jj) {
        const unsigned char* bxp = xr + (size_t)(j0 + jj) * DIM + s * CHUNK;
        const unsigned char* byp = yr + (size_t)(j0 + jj) * DIM + s * CHUNK;
        u32x4 bx[GPC], by[GPC];
        SLOADX4(bx[0], bxp, "0x0");  SLOADX4(bx[1], bxp, "0x10");
        SLOADX4(bx[2], bxp, "0x20"); SLOADX4(bx[3], bxp, "0x30");
        SLOADX4(bx[4], bxp, "0x40"); SLOADX4(bx[5], bxp, "0x50");
        SLOADX4(bx[6], bxp, "0x60"); SLOADX4(bx[7], bxp, "0x70");
        SLOADX4(by[0], byp, "0x0");  SLOADX4(by[1], byp, "0x10");
        SLOADX4(by[2], byp, "0x20"); SLOADX4(by[3], byp, "0x30");
        SLOADX4(by[4], byp, "0x40"); SLOADX4(by[5], byp, "0x50");
        SLOADX4(by[6], byp, "0x60"); SLOADX4(by[7], byp, "0x70");
        asm volatile("s_waitcnt lgkmcnt(0)");
        __builtin_amdgcn_sched_barrier(0);   // rule #18

        unsigned px0 = 0, px1 = 0, px2 = 0, px3 = 0;
        unsigned py0 = 0, py1 = 0, py2 = 0, py3 = 0;
        SADS(px0, ax[0].x, bx[0].x); SADS(px1, ax[0].y, bx[0].y);
        SADS(px2, ax[0].z, bx[0].z); SADS(px3, ax[0].w, bx[0].w);
        SADS(py0, ay[0].x, by[0].x); SADS(py1, ay[0].y, by[0].y);
        SADS(py2, ay[0].z, by[0].z); SADS(py3, ay[0].w, by[0].w);
        SADS(px0, ax[1].x, bx[1].x); SADS(px1, ax[1].y, bx[1].y);
        SADS(px2, ax[1].z, bx[1].z); SADS(px3, ax[1].w, bx[1].w);
        SADS(py0, ay[1].x, by[1].x); SADS(py1, ay[1].y, by[1].y);
        SADS(py2, ay[1].z, by[1].z); SADS(py3, ay[1].w, by[1].w);
        SADS(px0, ax[2].x, bx[2].x); SADS(px1, ax[2].y, bx[2].y);
        SADS(px2, ax[2].z, bx[2].z); SADS(px3, ax[2].w, bx[2].w);
        SADS(py0, ay[2].x, by[2].x); SADS(py1, ay[2].y, by[2].y);
        SADS(py2, ay[2].z, by[2].z); SADS(py3, ay[2].w, by[2].w);
        SADS(px0, ax[3].x, bx[3].x); SADS(px1, ax[3].y, bx[3].y);
        SADS(px2, ax[3].z, bx[3].z); SADS(px3, ax[3].w, bx[3].w);
        SADS(py0, ay[3].x, by[3].x); SADS(py1, ay[3].y, by[3].y);
        SADS(py2, ay[3].z, by[3].z); SADS(py3, ay[3].w, by[3].w);
        SADS(px0, ax[4].x, bx[4].x); SADS(px1, ax[4].y, bx[4].y);
        SADS(px2, ax[4].z, bx[4].z); SADS(px3, ax[4].w, bx[4].w);
        SADS(py0, ay[4].x, by[4].x); SADS(py1, ay[4].y, by[4].y);
        SADS(py2, ay[4].z, by[4].z); SADS(py3, ay[4].w, by[4].w);
        SADS(px0, ax[5].x, bx[5].x); SADS(px1, ax[5].y, bx[5].y);
        SADS(px2, ax[5].z, bx[5].z); SADS(px3, ax[5].w, bx[5].w);
        SADS(py0, ay[5].x, by[5].x); SADS(py1, ay[5].y, by[5].y);
        SADS(py2, ay[5].z, by[5].z); SADS(py3, ay[5].w, by[5].w);
        SADS(px0, ax[6].x, bx[6].x); SADS(px1, ax[6].y, bx[6].y);
        SADS(px2, ax[6].z, bx[6].z); SADS(px3, ax[6].w, bx[6].w);
        SADS(py0, ay[6].x, by[6].x); SADS(py1, ay[6].y, by[6].y);
        SADS(py2, ay[6].z, by[6].z); SADS(py3, ay[6].w, by[6].w);
        SADS(px0, ax[7].x, bx[7].x); SADS(px1, ax[7].y, bx[7].y);
        SADS(px2, ax[7].z, bx[7].z); SADS(px3, ax[7].w, bx[7].w);
        SADS(py0, ay[7].x, by[7].x); SADS(py1, ay[7].y, by[7].y);
        SADS(py2, ay[7].z, by[7].z); SADS(py3, ay[7].w, by[7].w);
        accx[jj] = (px0 + px1) + (px2 + px3);
        accy[jj] = (py0 + py1) + (py2 + py3);
    }

    // u16 partials (<= 128*255 = 32640), layout Pp[s][i][j]
    const size_t off16 = ((size_t)s * BATCH + i) * BATCH + j0;
    uint4 pv = make_uint4(accx[0] | (accx[1] << 16), accx[2] | (accx[3] << 16),
                          accx[4] | (accx[5] << 16), accx[6] | (accx[7] << 16));
    uint4 qv = make_uint4(accy[0] | (accy[1] << 16), accy[2] | (accy[3] << 16),
                          accy[4] | (accy[5] << 16), accy[6] | (accy[7] << 16));
    *(uint4*)(Pp + off16 / 2) = pv;
    *(uint4*)(Qp + off16 / 2) = qv;
}

// out[i] = -sum_j (sum_s P)(sum_s Q) / (16*4096)^2 — fixed-order, deterministic.
__global__ __launch_bounds__(256)
void reduce_out(const unsigned short* __restrict__ Pp, const unsigned short* __restrict__ Qp,
                float* __restrict__ out) {
    const int i = blockIdx.x;
    const int t = threadIdx.x;
    const int w = t >> 6, l = t & 63;

    unsigned p[4] = {0, 0, 0, 0}, q[4] = {0, 0, 0, 0};
#pragma unroll
    for (int ss = 0; ss < NS / 4; ++ss) {
        const int s = w * (NS / 4) + ss;
        const size_t base = ((size_t)s * BATCH + i) * BATCH + 4 * l;
        uint2 pv = *(const uint2*)(Pp + base);
        uint2 qv = *(const uint2*)(Qp + base);
        p[0] += pv.x & 0xffffu; p[1] += pv.x >> 16;
        p[2] += pv.y & 0xffffu; p[3] += pv.y >> 16;
        q[0] += qv.x & 0xffffu; q[1] += qv.x >> 16;
        q[2] += qv.y & 0xffffu; q[3] += qv.y >> 16;
    }

    __shared__ unsigned rp[4][64][4], rq[4][64][4];
#pragma unroll
    for (int e = 0; e < 4; ++e) { rp[w][l][e] = p[e]; rq[w][l][e] = q[e]; }
    __syncthreads();

    if (t < 64) {
        const float c2 = 1.0f / (16.0f * 4096.0f);
        float v = 0.0f;
#pragma unroll
        for (int e = 0; e < 4; ++e) {
            unsigned P = rp[0][t][e] + rp[1][t][e] + rp[2][t][e] + rp[3][t][e];
            unsigned Q = rq[0][t][e] + rq[1][t][e] + rq[2][t][e] + rq[3][t][e];
            v += ((float)P * c2) * ((float)Q * c2);
        }
#pragma unroll
        for (int off = 32; off >= 1; off >>= 1)
            v += __shfl_down(v, off, 64);
        if (t == 0) out[i] = -v;
    }
}

extern "C" void kernel_launch(void* const* d_in, const int* in_sizes, int n_in,
                              void* d_out, int out_size, void* d_ws, size_t ws_size,
                              hipStream_t stream) {
    const float* x = (const float*)d_in[0];
    const float* y = (const float*)d_in[1];
    float* out = (float*)d_out;

    // ws: qTx 1MB | qTy 1MB | qRx 1MB | qRy 1MB | Pp u16 4MB | Qp u16 4MB
    unsigned* qTx = (unsigned*)d_ws;
    unsigned* qTy = qTx + (size_t)BATCH * (DIM / 4);
    unsigned* qRx = qTy + (size_t)BATCH * (DIM / 4);
    unsigned* qRy = qRx + (size_t)BATCH * (DIM / 4);
    unsigned short* Pp = (unsigned short*)(qRy + (size_t)BATCH * (DIM / 4));
    unsigned short* Qp = Pp + (size_t)NS * BATCH * BATCH;

    quantize_t<<<512, 256, 0, stream>>>(x, y, qTx, qTy, qRx, qRy);
    pairwise_sad<<<dim3(NJB, NS), 256, 0, stream>>>(
        (const u32x4*)qTx, (const u32x4*)qTy,
        (const unsigned char*)qRx, (const unsigned char*)qRy,
        (unsigned*)Pp, (unsigned*)Qp);
    reduce_out<<<BATCH, 256, 0, stream>>>(Pp, Qp, out);
}